// Round 1
// baseline (42395.007 us; speedup 1.0000x reference)
//
#include <hip/hip_runtime.h>
#include <hip/hip_cooperative_groups.h>

namespace cg = cooperative_groups;

#define B_      32
#define N_      256
#define BN      (B_ * N_)
#define NSTEPS  100
#define SAVEEV  10
#define THREADS 512

// Dopri5 A-coefficients (fp32, matching jnp's f32 arithmetic on python-float coeffs)
__device__ __constant__ float c_Af[6][5] = {
    {0.f, 0.f, 0.f, 0.f, 0.f},
    {0.2f, 0.f, 0.f, 0.f, 0.f},
    {3.f/40.f, 9.f/40.f, 0.f, 0.f, 0.f},
    {44.f/45.f, -56.f/15.f, 32.f/9.f, 0.f, 0.f},
    {19372.f/6561.f, -25360.f/2187.f, 64448.f/6561.f, -212.f/729.f, 0.f},
    {9017.f/3168.f, -355.f/33.f, 46732.f/5247.f, 49.f/176.f, -5103.f/18656.f},
};

__device__ __forceinline__ float tanh_fast(float x) {
    // tanh(x) = 1 - 2/(e^{2x}+1); robust at +-inf, abs err ~1e-7
    float e2 = __expf(x + x);
    return 1.0f - 2.0f / (e2 + 1.0f);
}

__global__ void __launch_bounds__(THREADS, 1)
ode_kernel(const float* __restrict__ y0,
           const float* __restrict__ bias,
           const float* __restrict__ adj,
           const float* __restrict__ Kw,
           float* __restrict__ out,
           float* kbuf)   // ws: ping-pong k-buffers, 2 * 6 * BN floats
{
    cg::grid_group grid = cg::this_grid();
    const int l     = blockIdx.x;     // output column / 'l' index, 256 blocks
    const int tid   = threadIdx.x;    // 512 threads = 8 waves
    const int lane  = tid & 63;
    const int w     = tid >> 6;       // wave id 0..7
    const int m     = tid & 255;      // owned 'm' row of K[l]
    const int bh    = tid >> 8;       // 0/1: which half of the 32 b's
    const int bbase = bh << 4;

    __shared__ float s_loc[BN];       // current state s_n (block-private copy)
    __shared__ float s_i[BN];         // stage state
    __shared__ float adj_l[BN];       // adj[:, l, :]
    __shared__ float wred[8][16];
    __shared__ float bcol[B_];

    // one-time loads: adj slice, bias column, state init, out row 0
    for (int idx = tid; idx < BN; idx += THREADS) {
        const int b = idx >> 8, mm = idx & 255;
        adj_l[idx] = adj[(((size_t)(b << 8) + (size_t)l) << 8) + mm];
        s_loc[idx] = y0[idx];
    }
    if (tid < B_) {
        bcol[tid] = bias[(tid << 8) + l];          // bias[b][l][0]
        out[(tid << 8) + l] = y0[(tid << 8) + l];  // out[0] = y0
    }

    // Closed-form stage factors for the linear components (double precision)
    const float  dtf = 1.0f / 100.0f;  // == (ts[-1]-ts[0])/100 in f32
    const double dt  = (double)dtf;
    double sg[6];
    sg[0] = 1.0;
    sg[1] = 1.0 + dt*(0.2*sg[0]);
    sg[2] = 1.0 + dt*((3.0/40.0)*sg[0] + (9.0/40.0)*sg[1]);
    sg[3] = 1.0 + dt*((44.0/45.0)*sg[0] + (-56.0/15.0)*sg[1] + (32.0/9.0)*sg[2]);
    sg[4] = 1.0 + dt*((19372.0/6561.0)*sg[0] + (-25360.0/2187.0)*sg[1]
                    + (64448.0/6561.0)*sg[2] + (-212.0/729.0)*sg[3]);
    sg[5] = 1.0 + dt*((9017.0/3168.0)*sg[0] + (-355.0/33.0)*sg[1]
                    + (46732.0/5247.0)*sg[2] + (49.0/176.0)*sg[3]
                    + (-5103.0/18656.0)*sg[4]);
    const double Rf = 1.0 + dt*((35.0/384.0)*sg[0] + (500.0/1113.0)*sg[2]
                              + (125.0/192.0)*sg[3] + (-2187.0/6784.0)*sg[4]
                              + (11.0/84.0)*sg[5]);

    const float4* K4  = reinterpret_cast<const float4*>(Kw) + (((size_t)l << 8) + (size_t)m) * 64;
    const float4* sI4 = reinterpret_cast<const float4*>(s_i);

    __syncthreads();

    double e = 1.0;  // R^n
    for (int n = 0; n < NSTEPS; ++n) {
        float* kb = kbuf + (size_t)(n & 1) * (6 * BN);

        for (int st = 0; st < 6; ++st) {
            // build stage state s_i = s_n + dt * sum_j A[st][j] k_j
            if (st == 0) {
                for (int idx = tid; idx < BN; idx += THREADS) s_i[idx] = s_loc[idx];
            } else {
                for (int idx = tid; idx < BN; idx += THREADS) {
                    float t = c_Af[st][0] * kb[idx];
                    for (int jj = 1; jj < st; ++jj)
                        t = fmaf(c_Af[st][jj], kb[jj * BN + idx], t);
                    s_i[idx] = fmaf(dtf, t, s_loc[idx]);
                }
            }
            __syncthreads();

            // dot[b] = sum_j K[l, m, j] * s_i[b, j]  for 16 b's
            float acc[16];
            #pragma unroll
            for (int i = 0; i < 16; ++i) acc[i] = 0.f;

            for (int jo = 0; jo < 8; ++jo) {
                float4 kv[8];
                #pragma unroll
                for (int q = 0; q < 8; ++q) kv[q] = K4[(jo << 3) + q];
                #pragma unroll
                for (int q = 0; q < 8; ++q) {
                    const int j4 = (jo << 3) + q;
                    #pragma unroll
                    for (int bb = 0; bb < 16; ++bb) {
                        float4 sv = sI4[((bbase + bb) << 6) + j4];
                        acc[bb] = fmaf(kv[q].x, sv.x,
                                  fmaf(kv[q].y, sv.y,
                                  fmaf(kv[q].z, sv.z,
                                  fmaf(kv[q].w, sv.w, acc[bb]))));
                    }
                }
            }

            // part[b] = adj0[b,l,m] * tanh(dot[b]); reduce over m (64 lanes, then 4 m-waves)
            float part[16];
            #pragma unroll
            for (int bb = 0; bb < 16; ++bb)
                part[bb] = adj_l[((bbase + bb) << 8) + m] * tanh_fast(acc[bb]);

            #pragma unroll
            for (int off = 32; off > 0; off >>= 1) {
                #pragma unroll
                for (int bb = 0; bb < 16; ++bb)
                    part[bb] += __shfl_xor(part[bb], off, 64);
            }
            if (lane == 0) {
                #pragma unroll
                for (int bb = 0; bb < 16; ++bb) wred[w][bb] = part[bb];
            }
            __syncthreads();

            if (tid < B_) {
                const int g = tid >> 4, bb = tid & 15;
                float r = wred[(g << 2) + 0][bb] + wred[(g << 2) + 1][bb]
                        + wred[(g << 2) + 2][bb] + wred[(g << 2) + 3][bb];
                float scale = (float)(sg[st] * e);
                kb[st * BN + (tid << 8) + l] = scale * (bcol[tid] - r);
            }
            grid.sync();  // k_st visible to all blocks
        }

        // step update on block-private state: s += dt * sum(bw_i k_i)
        for (int idx = tid; idx < BN; idx += THREADS) {
            float t =        (35.0f/384.0f)   * kb[idx];
            t = fmaf( (500.0f/1113.0f),  kb[2 * BN + idx], t);
            t = fmaf( (125.0f/192.0f),   kb[3 * BN + idx], t);
            t = fmaf((-2187.0f/6784.0f), kb[4 * BN + idx], t);
            t = fmaf( (11.0f/84.0f),     kb[5 * BN + idx], t);
            s_loc[idx] = fmaf(dtf, t, s_loc[idx]);
        }
        e *= Rf;
        __syncthreads();
        if (((n + 1) % SAVEEV) == 0 && tid < B_) {
            const int row = (n + 1) / SAVEEV;
            out[(size_t)row * BN + (tid << 8) + l] = s_loc[(tid << 8) + l];
        }
        // no grid sync needed here: next step's stage-0 writes target the OTHER
        // ping-pong kbuf, and its stage-1 writes happen only after a grid.sync
        // that all blocks' step-update reads precede.
    }
}

extern "C" void kernel_launch(void* const* d_in, const int* in_sizes, int n_in,
                              void* d_out, int out_size, void* d_ws, size_t ws_size,
                              hipStream_t stream) {
    const float* y0   = (const float*)d_in[1];
    const float* bias = (const float*)d_in[2];
    const float* adj  = (const float*)d_in[3];
    const float* Kw   = (const float*)d_in[4];
    float* out  = (float*)d_out;
    float* kbuf = (float*)d_ws;   // needs 2*6*8192*4 = 384 KiB

    void* args[] = { (void*)&y0, (void*)&bias, (void*)&adj, (void*)&Kw,
                     (void*)&out, (void*)&kbuf };
    hipLaunchCooperativeKernel((const void*)ode_kernel,
                               dim3(256), dim3(THREADS), args, 0, stream);
}

// Round 2
// 24741.798 us; speedup vs baseline: 1.7135x; 1.7135x over previous
//
#include <hip/hip_runtime.h>
#include <hip/hip_cooperative_groups.h>

namespace cg = cooperative_groups;

#define B_      32
#define N_      256
#define BN      (B_ * N_)
#define NSTEPS  100
#define SAVEEV  10
#define THREADS 512

#define SPAD    264   // bf16 row stride for s_hi/s_lo (bank-balanced)
#define APAD    260   // f32 row stride for adj slice

typedef __attribute__((ext_vector_type(8))) short bf16x8;
typedef __attribute__((ext_vector_type(4))) float f32x4;

// Dopri5 A-coefficients (fp32, matching jnp's f32 arithmetic)
__device__ __constant__ float c_Af[6][5] = {
    {0.f, 0.f, 0.f, 0.f, 0.f},
    {0.2f, 0.f, 0.f, 0.f, 0.f},
    {3.f/40.f, 9.f/40.f, 0.f, 0.f, 0.f},
    {44.f/45.f, -56.f/15.f, 32.f/9.f, 0.f, 0.f},
    {19372.f/6561.f, -25360.f/2187.f, 64448.f/6561.f, -212.f/729.f, 0.f},
    {9017.f/3168.f, -355.f/33.f, 46732.f/5247.f, 49.f/176.f, -5103.f/18656.f},
};

__device__ __forceinline__ float tanh_fast(float x) {
    float e2 = __expf(x + x);
    return 1.0f - 2.0f / (e2 + 1.0f);
}

__device__ __forceinline__ unsigned short f2bf(float v) {
    union { float f; unsigned u; } x; x.f = v;
    unsigned r = (x.u + 0x7FFFu + ((x.u >> 16) & 1u)) >> 16;
    return (unsigned short)r;
}
__device__ __forceinline__ float bf2f(unsigned short h) {
    union { unsigned u; float f; } x; x.u = (unsigned)h << 16;
    return x.f;
}
__device__ __forceinline__ void split2(float v, unsigned short& h, unsigned short& lo) {
    h = f2bf(v);
    lo = f2bf(v - bf2f(h));
}

#define MFMA(a, b, c) __builtin_amdgcn_mfma_f32_16x16x32_bf16((a), (b), (c), 0, 0, 0)

__global__ void __launch_bounds__(THREADS)
ode_kernel(const float* __restrict__ y0,
           const float* __restrict__ bias,
           const float* __restrict__ adj,
           const float* __restrict__ Kw,
           float* __restrict__ out,
           float* kbuf)   // ws: ping-pong k-buffers, 2 * 6 * BN floats
{
    cg::grid_group grid = cg::this_grid();
    const int l    = blockIdx.x;       // output column 'l', 256 blocks
    const int tid  = threadIdx.x;      // 512 threads = 8 waves
    const int lane = tid & 63;
    const int w    = tid >> 6;         // wave 0..7, owns m rows [w*32, w*32+32)
    const int hh   = lane >> 4;        // k-group 0..3
    const int ln15 = lane & 15;

    __shared__ alignas(16) unsigned short shi[B_ * SPAD];
    __shared__ alignas(16) unsigned short slo[B_ * SPAD];
    __shared__ alignas(16) float s_loc[BN];
    __shared__ alignas(16) float adj_l[B_ * APAD];
    __shared__ float wred[8][B_];
    __shared__ float bcol[B_];

    // one-time loads
    for (int idx = tid; idx < BN; idx += THREADS) {
        const int b = idx >> 8, mm = idx & 255;
        adj_l[b * APAD + mm] = adj[(((size_t)(b << 8) + (size_t)l) << 8) + mm];
        s_loc[idx] = y0[idx];
    }
    if (tid < B_) {
        bcol[tid] = bias[(tid << 8) + l];
        out[(tid << 8) + l] = y0[(tid << 8) + l];
    }

    // K[l] -> register A-fragments (hi/lo bf16), once. 128 VGPRs.
    bf16x8 khi[2][8], klo[2][8];
    #pragma unroll
    for (int mt = 0; mt < 2; ++mt) {
        #pragma unroll
        for (int jt = 0; jt < 8; ++jt) {
            const int m  = w * 32 + mt * 16 + ln15;
            const int j0 = jt * 32 + hh * 8;
            const float* kp = Kw + ((size_t)l << 16) + (size_t)m * 256 + j0;
            float vv[8];
            *(float4*)(&vv[0]) = *(const float4*)(kp);
            *(float4*)(&vv[4]) = *(const float4*)(kp + 4);
            #pragma unroll
            for (int q = 0; q < 8; ++q) {
                unsigned short h, lo2;
                split2(vv[q], h, lo2);
                khi[mt][jt][q] = (short)h;
                klo[mt][jt][q] = (short)lo2;
            }
        }
    }

    // closed-form factors for the linear (bias, adj) components
    const float  dtf = 1.0f / 100.0f;
    const double dt  = (double)dtf;
    double sg[6];
    sg[0] = 1.0;
    sg[1] = 1.0 + dt*(0.2*sg[0]);
    sg[2] = 1.0 + dt*((3.0/40.0)*sg[0] + (9.0/40.0)*sg[1]);
    sg[3] = 1.0 + dt*((44.0/45.0)*sg[0] + (-56.0/15.0)*sg[1] + (32.0/9.0)*sg[2]);
    sg[4] = 1.0 + dt*((19372.0/6561.0)*sg[0] + (-25360.0/2187.0)*sg[1]
                    + (64448.0/6561.0)*sg[2] + (-212.0/729.0)*sg[3]);
    sg[5] = 1.0 + dt*((9017.0/3168.0)*sg[0] + (-355.0/33.0)*sg[1]
                    + (46732.0/5247.0)*sg[2] + (49.0/176.0)*sg[3]
                    + (-5103.0/18656.0)*sg[4]);
    const double Rf = 1.0 + dt*((35.0/384.0)*sg[0] + (500.0/1113.0)*sg[2]
                              + (125.0/192.0)*sg[3] + (-2187.0/6784.0)*sg[4]
                              + (11.0/84.0)*sg[5]);

    __syncthreads();

    double e = 1.0;  // R^n
    for (int n = 0; n < NSTEPS; ++n) {
        float* kb = kbuf + (size_t)(n & 1) * (6 * BN);

        for (int st = 0; st < 6; ++st) {
            // build stage state s_i -> (shi, slo) bf16 split in LDS
            if (st == 0) {
                for (int idx = tid; idx < BN; idx += THREADS) {
                    const int b = idx >> 8, j = idx & 255;
                    unsigned short h, lo2;
                    split2(s_loc[idx], h, lo2);
                    shi[b * SPAD + j] = h;
                    slo[b * SPAD + j] = lo2;
                }
            } else {
                for (int idx = tid; idx < BN; idx += THREADS) {
                    const int b = idx >> 8, j = idx & 255;
                    float t = c_Af[st][0] * kb[idx];
                    for (int jj = 1; jj < st; ++jj)
                        t = fmaf(c_Af[st][jj], kb[jj * BN + idx], t);
                    float v = fmaf(dtf, t, s_loc[idx]);
                    unsigned short h, lo2;
                    split2(v, h, lo2);
                    shi[b * SPAD + j] = h;
                    slo[b * SPAD + j] = lo2;
                }
            }
            __syncthreads();

            // D[m,b] = K[l,m,:] . s_i[b,:]  via 3-term bf16-split MFMA
            f32x4 acc[2][2];
            #pragma unroll
            for (int mt = 0; mt < 2; ++mt)
                #pragma unroll
                for (int nt = 0; nt < 2; ++nt)
                    acc[mt][nt] = (f32x4){0.f, 0.f, 0.f, 0.f};

            #pragma unroll
            for (int jt = 0; jt < 8; ++jt) {
                const int jo = jt * 32 + hh * 8;
                bf16x8 bh0 = *(const bf16x8*)&shi[(ln15     ) * SPAD + jo];
                bf16x8 bl0 = *(const bf16x8*)&slo[(ln15     ) * SPAD + jo];
                bf16x8 bh1 = *(const bf16x8*)&shi[(16 + ln15) * SPAD + jo];
                bf16x8 bl1 = *(const bf16x8*)&slo[(16 + ln15) * SPAD + jo];

                acc[0][0] = MFMA(khi[0][jt], bh0, acc[0][0]);
                acc[0][0] = MFMA(khi[0][jt], bl0, acc[0][0]);
                acc[0][0] = MFMA(klo[0][jt], bh0, acc[0][0]);

                acc[0][1] = MFMA(khi[0][jt], bh1, acc[0][1]);
                acc[0][1] = MFMA(khi[0][jt], bl1, acc[0][1]);
                acc[0][1] = MFMA(klo[0][jt], bh1, acc[0][1]);

                acc[1][0] = MFMA(khi[1][jt], bh0, acc[1][0]);
                acc[1][0] = MFMA(khi[1][jt], bl0, acc[1][0]);
                acc[1][0] = MFMA(klo[1][jt], bh0, acc[1][0]);

                acc[1][1] = MFMA(khi[1][jt], bh1, acc[1][1]);
                acc[1][1] = MFMA(khi[1][jt], bl1, acc[1][1]);
                acc[1][1] = MFMA(klo[1][jt], bh1, acc[1][1]);
            }

            // epilogue: pb[b] = sum_m adj[b,l,m] * tanh(D[m,b]) over wave's 32 m
            #pragma unroll
            for (int nt = 0; nt < 2; ++nt) {
                const int b = nt * 16 + ln15;
                float pb = 0.f;
                #pragma unroll
                for (int mt = 0; mt < 2; ++mt) {
                    const int m0 = w * 32 + mt * 16 + hh * 4;
                    f32x4 av = *(const f32x4*)&adj_l[b * APAD + m0];
                    #pragma unroll
                    for (int r = 0; r < 4; ++r)
                        pb = fmaf(av[r], tanh_fast(acc[mt][nt][r]), pb);
                }
                pb += __shfl_xor(pb, 16, 64);
                pb += __shfl_xor(pb, 32, 64);
                if (hh == 0) wred[w][b] = pb;
            }
            __syncthreads();

            if (tid < B_) {
                float r = 0.f;
                #pragma unroll
                for (int ww = 0; ww < 8; ++ww) r += wred[ww][tid];
                const float scale = (float)(sg[st] * e);
                kb[st * BN + (tid << 8) + l] = scale * (bcol[tid] - r);
            }
            grid.sync();  // k_st visible to all blocks
        }

        // step update on block-private f32 state
        for (int idx = tid; idx < BN; idx += THREADS) {
            float t =        (35.0f/384.0f)   * kb[idx];
            t = fmaf( (500.0f/1113.0f),  kb[2 * BN + idx], t);
            t = fmaf( (125.0f/192.0f),   kb[3 * BN + idx], t);
            t = fmaf((-2187.0f/6784.0f), kb[4 * BN + idx], t);
            t = fmaf( (11.0f/84.0f),     kb[5 * BN + idx], t);
            s_loc[idx] = fmaf(dtf, t, s_loc[idx]);
        }
        e *= Rf;
        __syncthreads();
        if (((n + 1) % SAVEEV) == 0 && tid < B_) {
            const int row = (n + 1) / SAVEEV;
            out[(size_t)row * BN + (tid << 8) + l] = s_loc[(tid << 8) + l];
        }
        // next step's stage-0 writes target the OTHER ping-pong kbuf; safe.
    }
}

extern "C" void kernel_launch(void* const* d_in, const int* in_sizes, int n_in,
                              void* d_out, int out_size, void* d_ws, size_t ws_size,
                              hipStream_t stream) {
    const float* y0   = (const float*)d_in[1];
    const float* bias = (const float*)d_in[2];
    const float* adj  = (const float*)d_in[3];
    const float* Kw   = (const float*)d_in[4];
    float* out  = (float*)d_out;
    float* kbuf = (float*)d_ws;   // 2*6*8192*4 = 384 KiB

    void* args[] = { (void*)&y0, (void*)&bias, (void*)&adj, (void*)&Kw,
                     (void*)&out, (void*)&kbuf };
    hipLaunchCooperativeKernel((const void*)ode_kernel,
                               dim3(256), dim3(THREADS), args, 0, stream);
}

// Round 3
// 4595.152 us; speedup vs baseline: 9.2260x; 5.3843x over previous
//
#include <hip/hip_runtime.h>
#include <hip/hip_cooperative_groups.h>

namespace cg = cooperative_groups;

#define B_      32
#define N_      256
#define BN      (B_ * N_)
#define NSTEPS  100
#define SAVEEV  10
#define THREADS 512

#define SPAD    264   // bf16 row stride for s_hi/s_lo
#define APAD    260   // f32 row stride for adj slice

typedef __attribute__((ext_vector_type(8))) short bf16x8;
typedef __attribute__((ext_vector_type(4))) float f32x4;

// Dopri5 A-coefficients (fp32, matching jnp's f32 arithmetic)
__device__ __constant__ float c_Af[6][5] = {
    {0.f, 0.f, 0.f, 0.f, 0.f},
    {0.2f, 0.f, 0.f, 0.f, 0.f},
    {3.f/40.f, 9.f/40.f, 0.f, 0.f, 0.f},
    {44.f/45.f, -56.f/15.f, 32.f/9.f, 0.f, 0.f},
    {19372.f/6561.f, -25360.f/2187.f, 64448.f/6561.f, -212.f/729.f, 0.f},
    {9017.f/3168.f, -355.f/33.f, 46732.f/5247.f, 49.f/176.f, -5103.f/18656.f},
};

__device__ __forceinline__ float tanh_fast(float x) {
    float e2 = __expf(x + x);
    return 1.0f - 2.0f / (e2 + 1.0f);
}

__device__ __forceinline__ unsigned short f2bf(float v) {
    union { float f; unsigned u; } x; x.f = v;
    unsigned r = (x.u + 0x7FFFu + ((x.u >> 16) & 1u)) >> 16;
    return (unsigned short)r;
}
__device__ __forceinline__ float bf2f(unsigned short h) {
    union { unsigned u; float f; } x; x.u = (unsigned)h << 16;
    return x.f;
}
__device__ __forceinline__ void split2(float v, unsigned short& h, unsigned short& lo) {
    h = f2bf(v);
    lo = f2bf(v - bf2f(h));
}

#define MFMA(a, b, c) __builtin_amdgcn_mfma_f32_16x16x32_bf16((a), (b), (c), 0, 0, 0)

__global__ void __launch_bounds__(THREADS, 1)
ode_kernel(const float* __restrict__ y0,
           const float* __restrict__ bias,
           const float* __restrict__ adj,
           const float* __restrict__ Kw,
           float* __restrict__ out,
           unsigned* __restrict__ ws)
{
    cg::grid_group grid = cg::this_grid();
    const int l    = blockIdx.x;       // owned state column, 256 blocks
    const int tid  = threadIdx.x;      // 512 threads = 8 waves
    const int lane = tid & 63;
    const int w    = tid >> 6;         // wave 0..7, owns m rows [w*32, w*32+32)
    const int hh   = lane >> 4;        // k-group 0..3
    const int ln15 = lane & 15;

    unsigned* pub  = ws;               // 2 * BN packed u32 (hi<<16|lo), ping-pong
    unsigned* arrv = ws + 2 * BN;      // 8 striped arrive counters, 64B apart

    __shared__ alignas(16) unsigned short shi[B_ * SPAD];
    __shared__ alignas(16) unsigned short slo[B_ * SPAD];
    __shared__ alignas(16) float adj_l[B_ * APAD];
    __shared__ float wred[8][B_];

    // block-local per-lane (wave 0, lanes 0..31) column state
    float s_r = 0.f, b_r = 0.f;
    float k_r[6] = {0.f, 0.f, 0.f, 0.f, 0.f, 0.f};

    for (int idx = tid; idx < BN; idx += THREADS) {
        const int b = idx >> 8, mm = idx & 255;
        adj_l[b * APAD + mm] = adj[(((size_t)(b << 8) + (size_t)l) << 8) + mm];
    }
    if (tid < B_) {
        s_r = y0[(tid << 8) + l];
        b_r = bias[(tid << 8) + l];
        out[(tid << 8) + l] = s_r;     // row 0 = y0
    }

    // K[l] -> register A-fragments (hi/lo bf16), once.
    bf16x8 khi[2][8], klo[2][8];
    #pragma unroll
    for (int mt = 0; mt < 2; ++mt) {
        #pragma unroll
        for (int jt = 0; jt < 8; ++jt) {
            const int m  = w * 32 + mt * 16 + ln15;
            const int j0 = jt * 32 + hh * 8;
            const float* kp = Kw + ((size_t)l << 16) + (size_t)m * 256 + j0;
            float vv[8];
            *(float4*)(&vv[0]) = *(const float4*)(kp);
            *(float4*)(&vv[4]) = *(const float4*)(kp + 4);
            #pragma unroll
            for (int q = 0; q < 8; ++q) {
                unsigned short h, lo2;
                split2(vv[q], h, lo2);
                khi[mt][jt][q] = (short)h;
                klo[mt][jt][q] = (short)lo2;
            }
        }
    }

    // closed-form factors for the linear (bias, adj) components
    const float  dtf = 1.0f / 100.0f;
    const double dt  = (double)dtf;
    double sg[6];
    sg[0] = 1.0;
    sg[1] = 1.0 + dt*(0.2*sg[0]);
    sg[2] = 1.0 + dt*((3.0/40.0)*sg[0] + (9.0/40.0)*sg[1]);
    sg[3] = 1.0 + dt*((44.0/45.0)*sg[0] + (-56.0/15.0)*sg[1] + (32.0/9.0)*sg[2]);
    sg[4] = 1.0 + dt*((19372.0/6561.0)*sg[0] + (-25360.0/2187.0)*sg[1]
                    + (64448.0/6561.0)*sg[2] + (-212.0/729.0)*sg[3]);
    sg[5] = 1.0 + dt*((9017.0/3168.0)*sg[0] + (-355.0/33.0)*sg[1]
                    + (46732.0/5247.0)*sg[2] + (49.0/176.0)*sg[3]
                    + (-5103.0/18656.0)*sg[4]);
    const double Rf = 1.0 + dt*((35.0/384.0)*sg[0] + (500.0/1113.0)*sg[2]
                              + (125.0/192.0)*sg[3] + (-2187.0/6784.0)*sg[4]
                              + (11.0/84.0)*sg[5]);

    // reset arrive counters once per launch (deterministic across replays)
    if (blockIdx.x == 0 && tid < 8)
        __hip_atomic_store(&arrv[tid << 4], 0u, __ATOMIC_RELAXED, __HIP_MEMORY_SCOPE_AGENT);
    grid.sync();   // one cooperative sync; all flag sync below is hand-rolled

    double e = 1.0;      // R^n
    unsigned ep = 0;     // global stage ordinal, 0..599
    for (int n = 0; n < NSTEPS; ++n) {
        #pragma unroll
        for (int st = 0; st < 6; ++st) {
            // ---- publish own stage-state column (pre-split bf16 hi/lo) ----
            if (tid < B_) {
                float v = s_r;
                if (st > 0) {
                    float t = c_Af[st][0] * k_r[0];
                    #pragma unroll
                    for (int jj = 1; jj < 5; ++jj)
                        if (jj < st) t = fmaf(c_Af[st][jj], k_r[jj], t);
                    v = fmaf(dtf, t, v);
                }
                unsigned short h, lo2;
                split2(v, h, lo2);
                unsigned pk = ((unsigned)h << 16) | (unsigned)lo2;
                (void)__hip_atomic_exchange(&pub[(ep & 1u) * BN + (tid << 8) + l], pk,
                                            __ATOMIC_RELAXED, __HIP_MEMORY_SCOPE_AGENT);
            }
            if (tid == 0) {
                asm volatile("s_waitcnt vmcnt(0)" ::: "memory");  // exchanges at L3
                __hip_atomic_fetch_add(&arrv[(l & 7) << 4], 1u,
                                       __ATOMIC_RELAXED, __HIP_MEMORY_SCOPE_AGENT);
                // ---- spin until all 256 blocks published this epoch ----
                const unsigned tgt = (ep + 1u) << 8;
                for (;;) {
                    unsigned ssum = 0;
                    #pragma unroll
                    for (int c = 0; c < 8; ++c)
                        ssum += __hip_atomic_load(&arrv[c << 4],
                                                  __ATOMIC_RELAXED, __HIP_MEMORY_SCOPE_AGENT);
                    if (ssum >= tgt) break;
                    __builtin_amdgcn_s_sleep(1);
                }
                __builtin_amdgcn_fence(__ATOMIC_ACQUIRE, "agent");  // buffer_inv, no wb
            }
            __syncthreads();

            // ---- read all columns, unpack into LDS hi/lo ----
            {
                const uint4* pv = (const uint4*)(pub + (ep & 1u) * BN);
                const int b  = tid >> 4;
                const int j0 = (tid & 15) << 4;
                unsigned ww[16];
                *(uint4*)&ww[0]  = pv[(tid << 2) + 0];
                *(uint4*)&ww[4]  = pv[(tid << 2) + 1];
                *(uint4*)&ww[8]  = pv[(tid << 2) + 2];
                *(uint4*)&ww[12] = pv[(tid << 2) + 3];
                bf16x8 H[2], L[2];
                #pragma unroll
                for (int q = 0; q < 16; ++q) {
                    H[q >> 3][q & 7] = (short)(ww[q] >> 16);
                    L[q >> 3][q & 7] = (short)(ww[q] & 0xffffu);
                }
                *(bf16x8*)&shi[b * SPAD + j0]     = H[0];
                *(bf16x8*)&shi[b * SPAD + j0 + 8] = H[1];
                *(bf16x8*)&slo[b * SPAD + j0]     = L[0];
                *(bf16x8*)&slo[b * SPAD + j0 + 8] = L[1];
            }
            __syncthreads();

            // ---- D[m,b] = K[l,m,:] . s_i[b,:] via 3-term bf16-split MFMA ----
            f32x4 acc[2][2];
            #pragma unroll
            for (int mt = 0; mt < 2; ++mt)
                #pragma unroll
                for (int nt = 0; nt < 2; ++nt)
                    acc[mt][nt] = (f32x4){0.f, 0.f, 0.f, 0.f};

            #pragma unroll
            for (int jt = 0; jt < 8; ++jt) {
                const int jo = jt * 32 + hh * 8;
                bf16x8 bh0 = *(const bf16x8*)&shi[(ln15     ) * SPAD + jo];
                bf16x8 bl0 = *(const bf16x8*)&slo[(ln15     ) * SPAD + jo];
                bf16x8 bh1 = *(const bf16x8*)&shi[(16 + ln15) * SPAD + jo];
                bf16x8 bl1 = *(const bf16x8*)&slo[(16 + ln15) * SPAD + jo];

                acc[0][0] = MFMA(khi[0][jt], bh0, acc[0][0]);
                acc[0][0] = MFMA(khi[0][jt], bl0, acc[0][0]);
                acc[0][0] = MFMA(klo[0][jt], bh0, acc[0][0]);

                acc[0][1] = MFMA(khi[0][jt], bh1, acc[0][1]);
                acc[0][1] = MFMA(khi[0][jt], bl1, acc[0][1]);
                acc[0][1] = MFMA(klo[0][jt], bh1, acc[0][1]);

                acc[1][0] = MFMA(khi[1][jt], bh0, acc[1][0]);
                acc[1][0] = MFMA(khi[1][jt], bl0, acc[1][0]);
                acc[1][0] = MFMA(klo[1][jt], bh0, acc[1][0]);

                acc[1][1] = MFMA(khi[1][jt], bh1, acc[1][1]);
                acc[1][1] = MFMA(khi[1][jt], bl1, acc[1][1]);
                acc[1][1] = MFMA(klo[1][jt], bh1, acc[1][1]);
            }

            // ---- epilogue: pb[b] = sum_m adj[b,l,m] * tanh(D[m,b]) ----
            #pragma unroll
            for (int nt = 0; nt < 2; ++nt) {
                const int b = nt * 16 + ln15;
                float pb = 0.f;
                #pragma unroll
                for (int mt = 0; mt < 2; ++mt) {
                    const int m0 = w * 32 + mt * 16 + hh * 4;
                    f32x4 av = *(const f32x4*)&adj_l[b * APAD + m0];
                    #pragma unroll
                    for (int r = 0; r < 4; ++r)
                        pb = fmaf(av[r], tanh_fast(acc[mt][nt][r]), pb);
                }
                pb += __shfl_xor(pb, 16, 64);
                pb += __shfl_xor(pb, 32, 64);
                if (hh == 0) wred[w][b] = pb;
            }
            __syncthreads();

            if (tid < B_) {
                float r = 0.f;
                #pragma unroll
                for (int ww2 = 0; ww2 < 8; ++ww2) r += wred[ww2][tid];
                k_r[st] = (float)(sg[st] * e) * (b_r - r);
            }
            ++ep;
        }

        // ---- step update: purely block-local ----
        if (tid < B_) {
            float t =        (35.0f/384.0f)   * k_r[0];
            t = fmaf( (500.0f/1113.0f),  k_r[2], t);
            t = fmaf( (125.0f/192.0f),   k_r[3], t);
            t = fmaf((-2187.0f/6784.0f), k_r[4], t);
            t = fmaf( (11.0f/84.0f),     k_r[5], t);
            s_r = fmaf(dtf, t, s_r);
            if (((n + 1) % SAVEEV) == 0)
                out[(size_t)((n + 1) / SAVEEV) * BN + (tid << 8) + l] = s_r;
        }
        e *= Rf;
    }
}

extern "C" void kernel_launch(void* const* d_in, const int* in_sizes, int n_in,
                              void* d_out, int out_size, void* d_ws, size_t ws_size,
                              hipStream_t stream) {
    const float* y0   = (const float*)d_in[1];
    const float* bias = (const float*)d_in[2];
    const float* adj  = (const float*)d_in[3];
    const float* Kw   = (const float*)d_in[4];
    float* out    = (float*)d_out;
    unsigned* ws  = (unsigned*)d_ws;   // 2*BN u32 pub + 8 counters = ~65 KiB

    void* args[] = { (void*)&y0, (void*)&bias, (void*)&adj, (void*)&Kw,
                     (void*)&out, (void*)&ws };
    hipLaunchCooperativeKernel((const void*)ode_kernel,
                               dim3(256), dim3(THREADS), args, 0, stream);
}